// Round 1
// baseline (317.751 us; speedup 1.0000x reference)
//
#include <hip/hip_runtime.h>

#define NB 8
#define NC 19
#define HW (512*512)
#define NPIX (NB*HW)
#define RANK 183500u   // max(100000, int(262144*0.7)) = 183500, < n_pix-1

// Monotone float->uint key: ascending float order == ascending uint order.
__device__ __forceinline__ unsigned fkey(float f) {
    unsigned b = __float_as_uint(f);
    return (b & 0x80000000u) ? ~b : (b | 0x80000000u);
}
__device__ __forceinline__ float finv(unsigned u) {
    unsigned b = (u & 0x80000000u) ? (u & 0x7fffffffu) : ~u;
    return __uint_as_float(b);
}

// Kernel 1: per-pixel CE loss (replicates jax.nn.softmax + log(p+1e-7) in f32),
// writes losses into d_out (reused as scratch), accumulates per-batch presence
// bitmap of target values (0..18).
__global__ __launch_bounds__(256) void losses_kernel(
    const float* __restrict__ logits, const int* __restrict__ targets,
    float* __restrict__ losses, unsigned* __restrict__ present)
{
    int ii = blockIdx.x * blockDim.x + threadIdx.x;   // pixel-pair index
    if (ii >= NPIX / 2) return;
    int i = ii * 2;
    int b = i >> 18;              // / HW
    int p = i & (HW - 1);         // % HW
    const float* base = logits + (size_t)b * NC * HW + p;

    float2 x[NC];
    float m0 = -INFINITY, m1 = -INFINITY;
    #pragma unroll
    for (int c = 0; c < NC; ++c) {
        float2 v = *reinterpret_cast<const float2*>(base + (size_t)c * HW);
        x[c] = v;
        m0 = fmaxf(m0, v.x);
        m1 = fmaxf(m1, v.y);
    }
    int2 t = *reinterpret_cast<const int2*>(targets + i);
    float s0 = 0.f, s1 = 0.f, et0 = 0.f, et1 = 0.f;
    #pragma unroll
    for (int c = 0; c < NC; ++c) {
        float e0 = expf(x[c].x - m0);
        float e1 = expf(x[c].y - m1);
        s0 += e0;
        s1 += e1;
        if (c == t.x) et0 = e0;
        if (c == t.y) et1 = e1;
    }
    float l0 = 0.f, l1 = 0.f;
    unsigned mbit = 0u;
    if (t.x >= 0 && t.x < NC) { l0 = -logf(et0 / s0 + 1e-7f); mbit |= 1u << t.x; }
    if (t.y >= 0 && t.y < NC) { l1 = -logf(et1 / s1 + 1e-7f); mbit |= 1u << t.y; }
    *reinterpret_cast<float2*>(losses + i) = make_float2(l0, l1);

    // wave-reduce presence bits; all 128 pixels of a wave share one batch
    #pragma unroll
    for (int o = 1; o < 64; o <<= 1) mbit |= __shfl_xor(mbit, o);
    if ((threadIdx.x & 63) == 0) atomicOr(&present[b], mbit);
}

// Wave-parallel "find bin containing rank" over an LDS histogram.
// Called by all threads; lanes 0..63 do the work; result into sel[0]=bin, sel[1]=rank-within-bin.
__device__ void wave_find_bin(unsigned* hist, int nbins, unsigned rank, unsigned* sel)
{
    int lane = threadIdx.x;
    if (lane < 64) {
        int per = nbins >> 6;
        int base = lane * per;
        unsigned s = 0;
        for (int j = 0; j < per; ++j) s += hist[base + j];
        unsigned pre = s;
        #pragma unroll
        for (int o = 1; o < 64; o <<= 1) {
            unsigned t = __shfl_up(pre, o);
            if (lane >= o) pre += t;
        }
        unsigned excl = pre - s;
        if (rank >= excl && rank < excl + s) {   // exactly one lane
            unsigned rr = rank - excl, cum = 0;
            for (int j = 0; j < per; ++j) {
                unsigned c = hist[base + j];
                if (cum + c > rr) { sel[0] = (unsigned)(base + j); sel[1] = rr - cum; break; }
                cum += c;
            }
        }
    }
}

// Kernel 2: exact rank-183500 value per batch via 3-pass radix select (11/11/10 bits).
__global__ __launch_bounds__(1024) void select_kernel(
    const float* __restrict__ losses, float* __restrict__ thresh)
{
    __shared__ unsigned hist[2048];
    __shared__ unsigned sel[2];
    const int b = blockIdx.x;
    const int tid = threadIdx.x;
    const float4* L4 = reinterpret_cast<const float4*>(losses + (size_t)b * HW);

    // ---- pass 1: bits 21..31 ----
    for (int j = tid; j < 2048; j += 1024) hist[j] = 0;
    __syncthreads();
    for (int i = tid; i < HW / 4; i += 1024) {
        float4 v = L4[i];
        atomicAdd(&hist[fkey(v.x) >> 21], 1u);
        atomicAdd(&hist[fkey(v.y) >> 21], 1u);
        atomicAdd(&hist[fkey(v.z) >> 21], 1u);
        atomicAdd(&hist[fkey(v.w) >> 21], 1u);
    }
    __syncthreads();
    wave_find_bin(hist, 2048, RANK, sel);
    __syncthreads();
    unsigned p1 = sel[0], r1 = sel[1];
    __syncthreads();

    // ---- pass 2: bits 10..20 among keys with top-11 == p1 ----
    for (int j = tid; j < 2048; j += 1024) hist[j] = 0;
    __syncthreads();
    for (int i = tid; i < HW / 4; i += 1024) {
        float4 v = L4[i];
        unsigned u;
        u = fkey(v.x); if ((u >> 21) == p1) atomicAdd(&hist[(u >> 10) & 2047u], 1u);
        u = fkey(v.y); if ((u >> 21) == p1) atomicAdd(&hist[(u >> 10) & 2047u], 1u);
        u = fkey(v.z); if ((u >> 21) == p1) atomicAdd(&hist[(u >> 10) & 2047u], 1u);
        u = fkey(v.w); if ((u >> 21) == p1) atomicAdd(&hist[(u >> 10) & 2047u], 1u);
    }
    __syncthreads();
    wave_find_bin(hist, 2048, r1, sel);
    __syncthreads();
    unsigned p2 = sel[0], r2 = sel[1];
    unsigned pref22 = (p1 << 11) | p2;
    __syncthreads();

    // ---- pass 3: low 10 bits among keys with top-22 == pref22 ----
    if (tid < 1024) hist[tid] = 0;
    __syncthreads();
    for (int i = tid; i < HW / 4; i += 1024) {
        float4 v = L4[i];
        unsigned u;
        u = fkey(v.x); if ((u >> 10) == pref22) atomicAdd(&hist[u & 1023u], 1u);
        u = fkey(v.y); if ((u >> 10) == pref22) atomicAdd(&hist[u & 1023u], 1u);
        u = fkey(v.z); if ((u >> 10) == pref22) atomicAdd(&hist[u & 1023u], 1u);
        u = fkey(v.w); if ((u >> 10) == pref22) atomicAdd(&hist[u & 1023u], 1u);
    }
    __syncthreads();
    wave_find_bin(hist, 1024, r2, sel);
    __syncthreads();
    if (tid == 0) thresh[b] = finv((pref22 << 10) | sel[0]);
}

// Kernel 3: in-place losses -> selection flags.
__global__ __launch_bounds__(256) void emit_kernel(
    float* __restrict__ out, const float* __restrict__ thresh,
    const unsigned* __restrict__ present)
{
    int i4 = blockIdx.x * blockDim.x + threadIdx.x;
    if (i4 >= NPIX / 4) return;
    int i = i4 * 4;
    int b = i >> 18;
    int p = i & (HW - 1);
    float th = thresh[b];
    unsigned pm = present[b];
    float4 v = reinterpret_cast<float4*>(out)[i4];
    float4 o;
    o.x = ((v.x > th) || ((p + 0) < NC && ((pm >> (p + 0)) & 1u))) ? 1.f : 0.f;
    o.y = ((v.y > th) || ((p + 1) < NC && ((pm >> (p + 1)) & 1u))) ? 1.f : 0.f;
    o.z = ((v.z > th) || ((p + 2) < NC && ((pm >> (p + 2)) & 1u))) ? 1.f : 0.f;
    o.w = ((v.w > th) || ((p + 3) < NC && ((pm >> (p + 3)) & 1u))) ? 1.f : 0.f;
    reinterpret_cast<float4*>(out)[i4] = o;
}

extern "C" void kernel_launch(void* const* d_in, const int* in_sizes, int n_in,
                              void* d_out, int out_size, void* d_ws, size_t ws_size,
                              hipStream_t stream)
{
    const float* logits  = (const float*)d_in[0];
    const int*   targets = (const int*)d_in[1];
    float* out = (float*)d_out;            // doubles as the losses buffer (NPIX floats)
    float* thresh = (float*)d_ws;          // 8 floats
    unsigned* present = (unsigned*)((char*)d_ws + 64);  // 8 uints

    hipMemsetAsync(present, 0, NB * sizeof(unsigned), stream);
    losses_kernel<<<NPIX / 2 / 256, 256, 0, stream>>>(logits, targets, out, present);
    select_kernel<<<NB, 1024, 0, stream>>>(out, thresh);
    emit_kernel<<<NPIX / 4 / 256, 256, 0, stream>>>(out, thresh, present);
}

// Round 2
// 191.164 us; speedup vs baseline: 1.6622x; 1.6622x over previous
//
#include <hip/hip_runtime.h>

#define NB 8
#define NC 19
#define HW (512*512)
#define NPIX (NB*HW)
#define RANK 183500u   // max(100000, int(262144*0.7)), < n_pix-1
#define NBIN 4096
#define CAP  4096

// Monotone fixed-point binning of loss values (range [-1e-7, 16.12] -> [0, 4095]).
// Must be used identically in hist and compact kernels.
__device__ __forceinline__ int bin_of(float l) {
    int b = (int)((l + 1.0f) * 224.0f);
    return b < 0 ? 0 : (b > NBIN - 1 ? NBIN - 1 : b);
}

// ---------------- Kernel 1: per-pixel CE loss, 4 px/thread ----------------
// Math sequence identical to the round-1 passing kernel (same fmax order,
// same expf/logf, ascending-c sum) so loss bits match the numpy boundary.
__global__ __launch_bounds__(256, 4) void losses_kernel(
    const float* __restrict__ logits, const int* __restrict__ targets,
    float* __restrict__ losses, unsigned* __restrict__ present)
{
    int ii = blockIdx.x * 256 + threadIdx.x;   // float4 index
    int i = ii * 4;
    int b = i >> 18;              // / HW
    int p = i & (HW - 1);         // % HW
    const float* base = logits + (size_t)b * NC * HW + p;

    float4 x[NC];
    #pragma unroll
    for (int c = 0; c < NC; ++c)
        x[c] = *reinterpret_cast<const float4*>(base + (size_t)c * HW);

    float4 m = x[0];
    #pragma unroll
    for (int c = 1; c < NC; ++c) {
        m.x = fmaxf(m.x, x[c].x); m.y = fmaxf(m.y, x[c].y);
        m.z = fmaxf(m.z, x[c].z); m.w = fmaxf(m.w, x[c].w);
    }

    int4 t = *reinterpret_cast<const int4*>(targets + i);
    float4 s = make_float4(0.f, 0.f, 0.f, 0.f);
    float4 et = make_float4(0.f, 0.f, 0.f, 0.f);
    #pragma unroll
    for (int c = 0; c < NC; ++c) {
        float e0 = expf(x[c].x - m.x); s.x += e0; if (c == t.x) et.x = e0;
        float e1 = expf(x[c].y - m.y); s.y += e1; if (c == t.y) et.y = e1;
        float e2 = expf(x[c].z - m.z); s.z += e2; if (c == t.z) et.z = e2;
        float e3 = expf(x[c].w - m.w); s.w += e3; if (c == t.w) et.w = e3;
    }

    float4 o = make_float4(0.f, 0.f, 0.f, 0.f);
    unsigned mbit = 0u;
    if (t.x >= 0 && t.x < NC) { o.x = -logf(et.x / s.x + 1e-7f); mbit |= 1u << t.x; }
    if (t.y >= 0 && t.y < NC) { o.y = -logf(et.y / s.y + 1e-7f); mbit |= 1u << t.y; }
    if (t.z >= 0 && t.z < NC) { o.z = -logf(et.z / s.z + 1e-7f); mbit |= 1u << t.z; }
    if (t.w >= 0 && t.w < NC) { o.w = -logf(et.w / s.w + 1e-7f); mbit |= 1u << t.w; }
    *reinterpret_cast<float4*>(losses + i) = o;

    #pragma unroll
    for (int off = 1; off < 64; off <<= 1) mbit |= __shfl_xor(mbit, off);
    if ((threadIdx.x & 63) == 0) atomicOr(&present[b], mbit);
}

// ---------------- Kernel 2: per-batch 4096-bin histogram ----------------
__global__ __launch_bounds__(256) void hist_kernel(
    const float* __restrict__ losses, unsigned* __restrict__ ghist)
{
    __shared__ unsigned lh[NBIN];
    const int b = blockIdx.y;
    for (int j = threadIdx.x; j < NBIN; j += 256) lh[j] = 0;
    __syncthreads();
    const float4* L = reinterpret_cast<const float4*>(losses + (size_t)b * HW)
                      + (size_t)blockIdx.x * 2048;
    for (int j = threadIdx.x; j < 2048; j += 256) {
        float4 v = L[j];
        atomicAdd(&lh[bin_of(v.x)], 1u);
        atomicAdd(&lh[bin_of(v.y)], 1u);
        atomicAdd(&lh[bin_of(v.z)], 1u);
        atomicAdd(&lh[bin_of(v.w)], 1u);
    }
    __syncthreads();
    unsigned* gh = ghist + b * NBIN;
    for (int j = threadIdx.x; j < NBIN; j += 256) {
        unsigned v = lh[j];
        if (v) atomicAdd(&gh[j], v);
    }
}

// ---------------- Kernel 3: find rank bin per batch ----------------
__global__ void pick_kernel(const unsigned* __restrict__ ghist,
                            unsigned* __restrict__ info)
{
    __shared__ unsigned lh[NBIN];
    __shared__ unsigned ps[256];
    const int b = blockIdx.x;
    const unsigned* gh = ghist + b * NBIN;
    for (int j = threadIdx.x; j < NBIN; j += 256) lh[j] = gh[j];
    __syncthreads();
    unsigned s = 0;
    for (int j = 0; j < 16; ++j) s += lh[threadIdx.x * 16 + j];
    ps[threadIdx.x] = s;
    __syncthreads();
    if (threadIdx.x == 0) {
        unsigned cum = 0;
        int chunk = 0;
        while (chunk < 255 && cum + ps[chunk] <= RANK) { cum += ps[chunk]; ++chunk; }
        int T = chunk * 16;
        while (T < NBIN - 1 && cum + lh[T] <= RANK) { cum += lh[T]; ++T; }
        info[b * 2]     = (unsigned)T;
        info[b * 2 + 1] = RANK - cum;   // rank within bin T
    }
}

// ---------------- Kernel 4: compact rank-bin elements ----------------
__global__ __launch_bounds__(256) void compact_kernel(
    const float* __restrict__ losses, const unsigned* __restrict__ info,
    unsigned* __restrict__ count, float* __restrict__ cand)
{
    const int b = blockIdx.y;
    const int T = (int)info[b * 2];
    const int lane = threadIdx.x & 63;
    const float4* L = reinterpret_cast<const float4*>(losses + (size_t)b * HW)
                      + (size_t)blockIdx.x * 2048;
    for (int j = threadIdx.x; j < 2048; j += 256) {
        float4 v = L[j];
        float vals[4] = {v.x, v.y, v.z, v.w};
        #pragma unroll
        for (int q = 0; q < 4; ++q) {
            float val = vals[q];
            bool sel = (bin_of(val) == T);
            unsigned long long msk = __ballot(sel);
            if (msk) {
                int leader = __ffsll(msk) - 1;
                int pre = __popcll(msk & ((1ull << lane) - 1ull));
                unsigned base = 0;
                if (lane == leader) base = atomicAdd(&count[b], (unsigned)__popcll(msk));
                base = (unsigned)__shfl((int)base, leader);
                if (sel) {
                    unsigned idx = base + (unsigned)pre;
                    if (idx < CAP) cand[b * CAP + idx] = val;
                }
            }
        }
    }
}

// ---------------- Kernel 5: exact tie-aware rank select in bin ----------------
__global__ void final_kernel(const float* __restrict__ cand,
                             const unsigned* __restrict__ count,
                             const unsigned* __restrict__ info,
                             float* __restrict__ thresh)
{
    __shared__ float c[CAP];
    const int b = blockIdx.x;
    unsigned k = count[b];
    if (k > CAP) k = CAP;
    const unsigned r = info[b * 2 + 1];
    for (unsigned j = threadIdx.x; j < k; j += 256) c[j] = cand[b * CAP + j];
    __syncthreads();
    for (unsigned e = threadIdx.x; e < k; e += 256) {
        float v = c[e];
        unsigned less = 0, eq = 0;
        for (unsigned j = 0; j < k; ++j) {
            float u = c[j];
            less += (u < v);
            eq   += (u == v);
        }
        if (less <= r && r < less + eq) thresh[b] = v;
    }
}

// ---------------- Kernel 6: losses -> selection flags (in place) ----------------
__global__ __launch_bounds__(256) void emit_kernel(
    float* __restrict__ out, const float* __restrict__ thresh,
    const unsigned* __restrict__ present)
{
    int i4 = blockIdx.x * 256 + threadIdx.x;
    int i = i4 * 4;
    int b = i >> 18;
    int p = i & (HW - 1);
    float th = thresh[b];
    unsigned pm = present[b];
    float4 v = reinterpret_cast<float4*>(out)[i4];
    float4 o;
    o.x = ((v.x > th) || ((p + 0) < NC && ((pm >> (p + 0)) & 1u))) ? 1.f : 0.f;
    o.y = ((v.y > th) || ((p + 1) < NC && ((pm >> (p + 1)) & 1u))) ? 1.f : 0.f;
    o.z = ((v.z > th) || ((p + 2) < NC && ((pm >> (p + 2)) & 1u))) ? 1.f : 0.f;
    o.w = ((v.w > th) || ((p + 3) < NC && ((pm >> (p + 3)) & 1u))) ? 1.f : 0.f;
    reinterpret_cast<float4*>(out)[i4] = o;
}

extern "C" void kernel_launch(void* const* d_in, const int* in_sizes, int n_in,
                              void* d_out, int out_size, void* d_ws, size_t ws_size,
                              hipStream_t stream)
{
    const float* logits  = (const float*)d_in[0];
    const int*   targets = (const int*)d_in[1];
    float* out = (float*)d_out;   // doubles as the losses buffer (NPIX floats)

    // d_ws layout
    char* ws = (char*)d_ws;
    unsigned* ghist   = (unsigned*)(ws);                 // 8*4096 u32 = 131072 B
    unsigned* count   = (unsigned*)(ws + 131072);        // 8 u32
    unsigned* present = (unsigned*)(ws + 131104);        // 8 u32
    unsigned* info    = (unsigned*)(ws + 131136);        // 16 u32
    float*    thresh  = (float*)   (ws + 131200);        // 8 f32
    float*    cand    = (float*)   (ws + 131232);        // 8*4096 f32

    hipMemsetAsync(d_ws, 0, 131232, stream);  // ghist + count + present + info

    losses_kernel<<<NPIX / 4 / 256, 256, 0, stream>>>(logits, targets, out, present);
    hist_kernel<<<dim3(32, NB), 256, 0, stream>>>(out, ghist);
    pick_kernel<<<NB, 256, 0, stream>>>(ghist, info);
    compact_kernel<<<dim3(32, NB), 256, 0, stream>>>(out, info, count, cand);
    final_kernel<<<NB, 256, 0, stream>>>(cand, count, info, thresh);
    emit_kernel<<<NPIX / 4 / 256, 256, 0, stream>>>(out, thresh, present);
}

// Round 3
// 190.676 us; speedup vs baseline: 1.6664x; 1.0026x over previous
//
#include <hip/hip_runtime.h>

#define NB 8
#define NC 19
#define HW (512*512)
#define NPIX (NB*HW)
#define RANK 183500u   // max(100000, int(262144*0.7)), < n_pix-1
#define NBIN 4096
#define CAP  4096

// Monotone fixed-point binning of loss values (range [-1e-7, 16.12] -> [0, 4095]).
__device__ __forceinline__ int bin_of(float l) {
    int b = (int)((l + 1.0f) * 224.0f);
    return b < 0 ? 0 : (b > NBIN - 1 ? NBIN - 1 : b);
}

// Async 16B global->LDS (gfx950). LDS dest is wave-uniform base + lane*16.
__device__ __forceinline__ void load16_lds(const float* g, float* lds_base_uniform) {
    __builtin_amdgcn_global_load_lds(
        (const __attribute__((address_space(1))) unsigned int*)g,
        (__attribute__((address_space(3))) unsigned int*)lds_base_uniform,
        16, 0, 0);
}

// ---------------- Kernel 1: per-pixel CE loss via LDS-staged tile ----------------
// One wave per block; tile = 256 pixels x 19 channels staged async into LDS.
// FP sequence per pixel is bit-identical to the round-1/2 passing kernels:
// m = fmax chain ascending from x[0]; e = expf(x-m); s = ascending sum;
// loss = -logf(e_t/s + 1e-7f).
__global__ __launch_bounds__(64) void losses_kernel(
    const float* __restrict__ logits, const int* __restrict__ targets,
    float* __restrict__ losses, unsigned* __restrict__ present)
{
    __shared__ float xs[NC * 256];
    const int lane = threadIdx.x;            // 0..63
    const int tile = blockIdx.x * 256;       // first pixel of tile (256 | tile)
    const int b = tile >> 18;                // / HW
    const int p = tile & (HW - 1);           // % HW
    const float* base = logits + (size_t)b * NC * HW + p;

    // Issue all 19 channel loads async; each wave instr moves 1024B HBM->LDS.
    #pragma unroll
    for (int c = 0; c < NC; ++c)
        load16_lds(base + (size_t)c * HW + lane * 4, &xs[c * 256]);

    int4 t = *reinterpret_cast<const int4*>(targets + tile + lane * 4);

    asm volatile("s_waitcnt vmcnt(0)" ::: "memory");
    __builtin_amdgcn_sched_barrier(0);

    // pass 1: channel max (ds_read_b128, conflict-free: 8-lane groups tile banks)
    float4 m = *reinterpret_cast<const float4*>(&xs[0 * 256 + lane * 4]);
    #pragma unroll
    for (int c = 1; c < NC; ++c) {
        float4 v = *reinterpret_cast<const float4*>(&xs[c * 256 + lane * 4]);
        m.x = fmaxf(m.x, v.x); m.y = fmaxf(m.y, v.y);
        m.z = fmaxf(m.z, v.z); m.w = fmaxf(m.w, v.w);
    }

    // pass 2: exp-sum (ascending) + gather target exp
    float4 s = make_float4(0.f, 0.f, 0.f, 0.f);
    float4 et = make_float4(0.f, 0.f, 0.f, 0.f);
    #pragma unroll
    for (int c = 0; c < NC; ++c) {
        float4 v = *reinterpret_cast<const float4*>(&xs[c * 256 + lane * 4]);
        float e0 = expf(v.x - m.x); s.x += e0; if (c == t.x) et.x = e0;
        float e1 = expf(v.y - m.y); s.y += e1; if (c == t.y) et.y = e1;
        float e2 = expf(v.z - m.z); s.z += e2; if (c == t.z) et.z = e2;
        float e3 = expf(v.w - m.w); s.w += e3; if (c == t.w) et.w = e3;
    }

    float4 o = make_float4(0.f, 0.f, 0.f, 0.f);
    unsigned mbit = 0u;
    if (t.x >= 0 && t.x < NC) { o.x = -logf(et.x / s.x + 1e-7f); mbit |= 1u << t.x; }
    if (t.y >= 0 && t.y < NC) { o.y = -logf(et.y / s.y + 1e-7f); mbit |= 1u << t.y; }
    if (t.z >= 0 && t.z < NC) { o.z = -logf(et.z / s.z + 1e-7f); mbit |= 1u << t.z; }
    if (t.w >= 0 && t.w < NC) { o.w = -logf(et.w / s.w + 1e-7f); mbit |= 1u << t.w; }
    *reinterpret_cast<float4*>(losses + tile + lane * 4) = o;

    #pragma unroll
    for (int off = 1; off < 64; off <<= 1) mbit |= __shfl_xor(mbit, off);
    if (lane == 0) atomicOr(&present[b], mbit);
}

// ---------------- Kernel 2: per-batch 4096-bin histogram ----------------
__global__ __launch_bounds__(256) void hist_kernel(
    const float* __restrict__ losses, unsigned* __restrict__ ghist)
{
    __shared__ unsigned lh[NBIN];
    const int b = blockIdx.y;
    for (int j = threadIdx.x; j < NBIN; j += 256) lh[j] = 0;
    __syncthreads();
    const float4* L = reinterpret_cast<const float4*>(losses + (size_t)b * HW)
                      + (size_t)blockIdx.x * 1024;
    for (int j = threadIdx.x; j < 1024; j += 256) {
        float4 v = L[j];
        atomicAdd(&lh[bin_of(v.x)], 1u);
        atomicAdd(&lh[bin_of(v.y)], 1u);
        atomicAdd(&lh[bin_of(v.z)], 1u);
        atomicAdd(&lh[bin_of(v.w)], 1u);
    }
    __syncthreads();
    unsigned* gh = ghist + b * NBIN;
    for (int j = threadIdx.x; j < NBIN; j += 256) {
        unsigned v = lh[j];
        if (v) atomicAdd(&gh[j], v);
    }
}

// ---------------- Kernel 3: find rank bin per batch ----------------
__global__ void pick_kernel(const unsigned* __restrict__ ghist,
                            unsigned* __restrict__ info)
{
    __shared__ unsigned lh[NBIN];
    __shared__ unsigned ps[256];
    const int b = blockIdx.x;
    const unsigned* gh = ghist + b * NBIN;
    for (int j = threadIdx.x; j < NBIN; j += 256) lh[j] = gh[j];
    __syncthreads();
    unsigned s = 0;
    for (int j = 0; j < 16; ++j) s += lh[threadIdx.x * 16 + j];
    ps[threadIdx.x] = s;
    __syncthreads();
    if (threadIdx.x == 0) {
        unsigned cum = 0;
        int chunk = 0;
        while (chunk < 255 && cum + ps[chunk] <= RANK) { cum += ps[chunk]; ++chunk; }
        int T = chunk * 16;
        while (T < NBIN - 1 && cum + lh[T] <= RANK) { cum += lh[T]; ++T; }
        info[b * 2]     = (unsigned)T;
        info[b * 2 + 1] = RANK - cum;   // rank within bin T
    }
}

// ---------------- Kernel 4: compact rank-bin elements ----------------
__global__ __launch_bounds__(256) void compact_kernel(
    const float* __restrict__ losses, const unsigned* __restrict__ info,
    unsigned* __restrict__ count, float* __restrict__ cand)
{
    const int b = blockIdx.y;
    const int T = (int)info[b * 2];
    const int lane = threadIdx.x & 63;
    const float4* L = reinterpret_cast<const float4*>(losses + (size_t)b * HW)
                      + (size_t)blockIdx.x * 1024;
    for (int j = threadIdx.x; j < 1024; j += 256) {
        float4 v = L[j];
        float vals[4] = {v.x, v.y, v.z, v.w};
        #pragma unroll
        for (int q = 0; q < 4; ++q) {
            float val = vals[q];
            bool sel = (bin_of(val) == T);
            unsigned long long msk = __ballot(sel);
            if (msk) {
                int leader = __ffsll(msk) - 1;
                int pre = __popcll(msk & ((1ull << lane) - 1ull));
                unsigned base = 0;
                if (lane == leader) base = atomicAdd(&count[b], (unsigned)__popcll(msk));
                base = (unsigned)__shfl((int)base, leader);
                if (sel) {
                    unsigned idx = base + (unsigned)pre;
                    if (idx < CAP) cand[b * CAP + idx] = val;
                }
            }
        }
    }
}

// ---------------- Kernel 5: exact tie-aware rank select in bin ----------------
__global__ void final_kernel(const float* __restrict__ cand,
                             const unsigned* __restrict__ count,
                             const unsigned* __restrict__ info,
                             float* __restrict__ thresh)
{
    __shared__ float c[CAP];
    const int b = blockIdx.x;
    unsigned k = count[b];
    if (k > CAP) k = CAP;
    const unsigned r = info[b * 2 + 1];
    for (unsigned j = threadIdx.x; j < k; j += 256) c[j] = cand[b * CAP + j];
    __syncthreads();
    for (unsigned e = threadIdx.x; e < k; e += 256) {
        float v = c[e];
        unsigned less = 0, eq = 0;
        for (unsigned j = 0; j < k; ++j) {
            float u = c[j];
            less += (u < v);
            eq   += (u == v);
        }
        if (less <= r && r < less + eq) thresh[b] = v;
    }
}

// ---------------- Kernel 6: losses -> selection flags (in place) ----------------
__global__ __launch_bounds__(256) void emit_kernel(
    float* __restrict__ out, const float* __restrict__ thresh,
    const unsigned* __restrict__ present)
{
    int i4 = blockIdx.x * 256 + threadIdx.x;
    int i = i4 * 4;
    int b = i >> 18;
    int p = i & (HW - 1);
    float th = thresh[b];
    unsigned pm = present[b];
    float4 v = reinterpret_cast<float4*>(out)[i4];
    float4 o;
    o.x = ((v.x > th) || ((p + 0) < NC && ((pm >> (p + 0)) & 1u))) ? 1.f : 0.f;
    o.y = ((v.y > th) || ((p + 1) < NC && ((pm >> (p + 1)) & 1u))) ? 1.f : 0.f;
    o.z = ((v.z > th) || ((p + 2) < NC && ((pm >> (p + 2)) & 1u))) ? 1.f : 0.f;
    o.w = ((v.w > th) || ((p + 3) < NC && ((pm >> (p + 3)) & 1u))) ? 1.f : 0.f;
    reinterpret_cast<float4*>(out)[i4] = o;
}

extern "C" void kernel_launch(void* const* d_in, const int* in_sizes, int n_in,
                              void* d_out, int out_size, void* d_ws, size_t ws_size,
                              hipStream_t stream)
{
    const float* logits  = (const float*)d_in[0];
    const int*   targets = (const int*)d_in[1];
    float* out = (float*)d_out;   // doubles as the losses buffer (NPIX floats)

    // d_ws layout
    char* ws = (char*)d_ws;
    unsigned* ghist   = (unsigned*)(ws);                 // 8*4096 u32 = 131072 B
    unsigned* count   = (unsigned*)(ws + 131072);        // 8 u32
    unsigned* present = (unsigned*)(ws + 131104);        // 8 u32
    unsigned* info    = (unsigned*)(ws + 131136);        // 16 u32
    float*    thresh  = (float*)   (ws + 131200);        // 8 f32
    float*    cand    = (float*)   (ws + 131232);        // 8*4096 f32

    hipMemsetAsync(d_ws, 0, 131232, stream);  // ghist + count + present + info

    losses_kernel<<<NPIX / 256, 64, 0, stream>>>(logits, targets, out, present);
    hist_kernel<<<dim3(64, NB), 256, 0, stream>>>(out, ghist);
    pick_kernel<<<NB, 256, 0, stream>>>(ghist, info);
    compact_kernel<<<dim3(64, NB), 256, 0, stream>>>(out, info, count, cand);
    final_kernel<<<NB, 256, 0, stream>>>(cand, count, info, thresh);
    emit_kernel<<<NPIX / 4 / 256, 256, 0, stream>>>(out, thresh, present);
}

// Round 4
// 135.260 us; speedup vs baseline: 2.3492x; 1.4097x over previous
//
#include <hip/hip_runtime.h>

#define NB 8
#define NC 19
#define HW (512*512)
#define NPIX (NB*HW)
#define RANK 183500u   // max(100000, int(262144*0.7)), < n_pix-1
#define NBIN 4096
#define CAP  4096
#define NT   8                      // tiles per losses-block (consecutive, same batch)
#define LGRID (NPIX / 256 / NT)     // 1024 blocks

__device__ __forceinline__ unsigned fkey(float f) {
    unsigned b = __float_as_uint(f);
    return (b & 0x80000000u) ? ~b : (b | 0x80000000u);
}
__device__ __forceinline__ float finv(unsigned u) {
    unsigned b = (u & 0x80000000u) ? (u & 0x7fffffffu) : ~u;
    return __uint_as_float(b);
}
__device__ __forceinline__ int bin_of(float l) {
    int b = (int)((l + 1.0f) * 224.0f);
    return b < 0 ? 0 : (b > NBIN - 1 ? NBIN - 1 : b);
}
__device__ __forceinline__ unsigned umn(unsigned a, unsigned b) { return a < b ? a : b; }
__device__ __forceinline__ unsigned umx(unsigned a, unsigned b) { return a > b ? a : b; }

// Async 16B/lane global->LDS (gfx950). LDS dest = wave-uniform base + lane*16.
__device__ __forceinline__ void load16_lds(const void* g, void* lds) {
    __builtin_amdgcn_global_load_lds(
        (const __attribute__((address_space(1))) unsigned int*)g,
        (__attribute__((address_space(3))) unsigned int*)lds, 16, 0, 0);
}

// ---------------- Kernel 1: CE losses, double-buffered counted-vmcnt pipeline ----
// 1 wave/block, 8 consecutive 256-px tiles/block. Per tile: 19 channel loads +
// 1 targets load async to LDS (20 vmem ops) + 1 loss store. Never drain vmcnt
// mid-loop: wait leaves the 20 prefetch loads (+1 old store) in flight.
// Per-pixel FP sequence is bit-identical to rounds 1-3 (absmax=0 pedigree).
__global__ __launch_bounds__(64) void losses_kernel(
    const float* __restrict__ logits, const int* __restrict__ targets,
    float* __restrict__ losses, unsigned* __restrict__ present)
{
    __shared__ float xs[2][20 * 256];           // 40960 B -> 4 blocks/CU
    const int lane = threadIdx.x;               // 0..63
    const int pix0 = blockIdx.x * (NT * 256);   // block's first pixel
    const int b = pix0 >> 18;                   // batch (all 8 tiles same batch)
    const int p0 = pix0 & (HW - 1);
    const float* cbase = logits + (size_t)b * NC * HW + p0;

    // prologue: issue tile 0 (20 loads)
    #pragma unroll
    for (int c = 0; c < NC; ++c)
        load16_lds(cbase + (size_t)c * HW + lane * 4, &xs[0][c * 256]);
    load16_lds(targets + pix0 + lane * 4, &xs[0][NC * 256]);

    unsigned mbit = 0u;
    for (int k = 0; k < NT; ++k) {
        const int cur = k & 1;
        if (k + 1 < NT) {   // issue tile k+1 into the other buffer (20 loads)
            const float* nbase = cbase + (k + 1) * 256;
            float* dst = &xs[cur ^ 1][0];
            #pragma unroll
            for (int c = 0; c < NC; ++c)
                load16_lds(nbase + (size_t)c * HW + lane * 4, dst + c * 256);
            load16_lds(targets + pix0 + (k + 1) * 256 + lane * 4, dst + NC * 256);
        }
        // counted wait: drain tile k's 20 loads only.
        // outstanding at this point: [loads(k):20][store(k-1):0/1][loads(k+1):0/20]
        if (k + 1 == NT)      asm volatile("s_waitcnt vmcnt(0)"  ::: "memory");
        else if (k == 0)      asm volatile("s_waitcnt vmcnt(20)" ::: "memory");
        else                  asm volatile("s_waitcnt vmcnt(21)" ::: "memory");
        __builtin_amdgcn_sched_barrier(0);

        const float* X = &xs[cur][0];
        float4 m = *reinterpret_cast<const float4*>(X + lane * 4);
        #pragma unroll
        for (int c = 1; c < NC; ++c) {
            float4 v = *reinterpret_cast<const float4*>(X + c * 256 + lane * 4);
            m.x = fmaxf(m.x, v.x); m.y = fmaxf(m.y, v.y);
            m.z = fmaxf(m.z, v.z); m.w = fmaxf(m.w, v.w);
        }
        int4 t = *reinterpret_cast<const int4*>(
                     reinterpret_cast<const int*>(X + NC * 256) + lane * 4);
        float4 s  = make_float4(0.f, 0.f, 0.f, 0.f);
        float4 et = make_float4(0.f, 0.f, 0.f, 0.f);
        #pragma unroll
        for (int c = 0; c < NC; ++c) {
            float4 v = *reinterpret_cast<const float4*>(X + c * 256 + lane * 4);
            float e0 = expf(v.x - m.x); s.x += e0; if (c == t.x) et.x = e0;
            float e1 = expf(v.y - m.y); s.y += e1; if (c == t.y) et.y = e1;
            float e2 = expf(v.z - m.z); s.z += e2; if (c == t.z) et.z = e2;
            float e3 = expf(v.w - m.w); s.w += e3; if (c == t.w) et.w = e3;
        }
        float4 o = make_float4(0.f, 0.f, 0.f, 0.f);
        if (t.x >= 0 && t.x < NC) { o.x = -logf(et.x / s.x + 1e-7f); mbit |= 1u << t.x; }
        if (t.y >= 0 && t.y < NC) { o.y = -logf(et.y / s.y + 1e-7f); mbit |= 1u << t.y; }
        if (t.z >= 0 && t.z < NC) { o.z = -logf(et.z / s.z + 1e-7f); mbit |= 1u << t.z; }
        if (t.w >= 0 && t.w < NC) { o.w = -logf(et.w / s.w + 1e-7f); mbit |= 1u << t.w; }
        *reinterpret_cast<float4*>(losses + pix0 + k * 256 + lane * 4) = o;  // 1 store
    }

    #pragma unroll
    for (int off = 1; off < 64; off <<= 1) mbit |= __shfl_xor(mbit, off);
    if (lane == 0) atomicOr(&present[b], mbit);
}

// ---------------- Kernel 2: per-batch 4096-bin histogram ----------------
__global__ __launch_bounds__(256) void hist_kernel(
    const float* __restrict__ losses, unsigned* __restrict__ ghist)
{
    __shared__ unsigned lh[NBIN];
    const int b = blockIdx.y;
    for (int j = threadIdx.x; j < NBIN; j += 256) lh[j] = 0;
    __syncthreads();
    const float4* L = reinterpret_cast<const float4*>(losses + (size_t)b * HW)
                      + (size_t)blockIdx.x * 1024;
    for (int j = threadIdx.x; j < 1024; j += 256) {
        float4 v = L[j];
        atomicAdd(&lh[bin_of(v.x)], 1u);
        atomicAdd(&lh[bin_of(v.y)], 1u);
        atomicAdd(&lh[bin_of(v.z)], 1u);
        atomicAdd(&lh[bin_of(v.w)], 1u);
    }
    __syncthreads();
    unsigned* gh = ghist + b * NBIN;
    for (int j = threadIdx.x; j < NBIN; j += 256) {
        unsigned v = lh[j];
        if (v) atomicAdd(&gh[j], v);
    }
}

// ---------------- Kernel 3: find rank bin per batch ----------------
__global__ void pick_kernel(const unsigned* __restrict__ ghist,
                            unsigned* __restrict__ info)
{
    __shared__ unsigned lh[NBIN];
    __shared__ unsigned ps[256];
    const int b = blockIdx.x;
    const unsigned* gh = ghist + b * NBIN;
    for (int j = threadIdx.x; j < NBIN; j += 256) lh[j] = gh[j];
    __syncthreads();
    unsigned s = 0;
    for (int j = 0; j < 16; ++j) s += lh[threadIdx.x * 16 + j];
    ps[threadIdx.x] = s;
    __syncthreads();
    if (threadIdx.x == 0) {
        unsigned cum = 0;
        int chunk = 0;
        while (chunk < 255 && cum + ps[chunk] <= RANK) { cum += ps[chunk]; ++chunk; }
        int T = chunk * 16;
        while (T < NBIN - 1 && cum + lh[T] <= RANK) { cum += lh[T]; ++T; }
        info[b * 2]     = (unsigned)T;
        info[b * 2 + 1] = RANK - cum;   // rank within bin T
    }
}

// ---------------- Kernel 4: compact rank-bin elements ----------------
__global__ __launch_bounds__(256) void compact_kernel(
    const float* __restrict__ losses, const unsigned* __restrict__ info,
    unsigned* __restrict__ count, float* __restrict__ cand)
{
    const int b = blockIdx.y;
    const int T = (int)info[b * 2];
    const int lane = threadIdx.x & 63;
    const float4* L = reinterpret_cast<const float4*>(losses + (size_t)b * HW)
                      + (size_t)blockIdx.x * 1024;
    for (int j = threadIdx.x; j < 1024; j += 256) {
        float4 v = L[j];
        float vals[4] = {v.x, v.y, v.z, v.w};
        #pragma unroll
        for (int q = 0; q < 4; ++q) {
            float val = vals[q];
            bool sel = (bin_of(val) == T);
            unsigned long long msk = __ballot(sel);
            if (msk) {
                int leader = __ffsll(msk) - 1;
                int pre = __popcll(msk & ((1ull << lane) - 1ull));
                unsigned base = 0;
                if (lane == leader) base = atomicAdd(&count[b], (unsigned)__popcll(msk));
                base = (unsigned)__shfl((int)base, leader);
                if (sel) {
                    unsigned idx = base + (unsigned)pre;
                    if (idx < CAP) cand[b * CAP + idx] = val;
                }
            }
        }
    }
}

// ---------------- Kernel 5: exact tie-aware rank select (two-level) ----------------
// min/max-reduce candidate fkeys, dynamic-shift 512-sub-bin histogram (monotone
// for ANY spread), scan to the rank sub-bin, tie-aware exact select on the few
// remaining elements. Semantics identical to the O(k^2) version.
__global__ __launch_bounds__(256) void final_kernel(
    const float* __restrict__ cand, const unsigned* __restrict__ count,
    const unsigned* __restrict__ info, float* __restrict__ thresh)
{
    __shared__ unsigned kf[CAP];
    __shared__ unsigned h[512];
    __shared__ unsigned sub[2048];
    __shared__ unsigned red[8];
    __shared__ unsigned kmin_sh, shift_sh, sb_sh, r2_sh, cnt_sh;
    const int tid = threadIdx.x, b = blockIdx.x;
    unsigned k = count[b]; if (k > CAP) k = CAP;
    const unsigned r = info[b * 2 + 1];

    for (unsigned j = tid; j < k; j += 256) kf[j] = fkey(cand[b * CAP + j]);
    for (int j = tid; j < 512; j += 256) h[j] = 0;
    __syncthreads();

    unsigned lmin = 0xFFFFFFFFu, lmax = 0u;
    for (unsigned j = tid; j < k; j += 256) { unsigned v = kf[j]; lmin = umn(lmin, v); lmax = umx(lmax, v); }
    #pragma unroll
    for (int o = 1; o < 64; o <<= 1) {
        lmin = umn(lmin, (unsigned)__shfl_xor((int)lmin, o));
        lmax = umx(lmax, (unsigned)__shfl_xor((int)lmax, o));
    }
    if ((tid & 63) == 0) { red[tid >> 6] = lmin; red[4 + (tid >> 6)] = lmax; }
    __syncthreads();
    if (tid == 0) {
        unsigned mn = red[0], mx = red[4];
        for (int w = 1; w < 4; ++w) { mn = umn(mn, red[w]); mx = umx(mx, red[4 + w]); }
        unsigned spread = mx - mn;
        int bits = 32 - __clz((int)(spread | 1u));
        shift_sh = (unsigned)(bits > 9 ? bits - 9 : 0);   // (spread>>shift) < 512
        kmin_sh = mn;
        cnt_sh = 0;
    }
    __syncthreads();
    const unsigned kmin = kmin_sh, shift = shift_sh;
    for (unsigned j = tid; j < k; j += 256) atomicAdd(&h[(kf[j] - kmin) >> shift], 1u);
    __syncthreads();
    if (tid == 0) {
        unsigned cum = 0; int sb = 0;
        while (sb < 511 && cum + h[sb] <= r) { cum += h[sb]; ++sb; }
        sb_sh = (unsigned)sb; r2_sh = r - cum;
    }
    __syncthreads();
    const unsigned sb = sb_sh;
    for (unsigned j = tid; j < k; j += 256) {
        if (((kf[j] - kmin) >> shift) == sb) {
            unsigned idx = atomicAdd(&cnt_sh, 1u);
            if (idx < 2048) sub[idx] = kf[j];
        }
    }
    __syncthreads();
    const unsigned k2 = umn(cnt_sh, 2048u), r2 = r2_sh;
    for (unsigned e = tid; e < k2; e += 256) {
        unsigned v = sub[e], less = 0, eq = 0;
        for (unsigned j = 0; j < k2; ++j) { unsigned u = sub[j]; less += (u < v); eq += (u == v); }
        if (less <= r2 && r2 < less + eq) thresh[b] = finv(v);
    }
}

// ---------------- Kernel 6: losses -> selection flags (in place) ----------------
__global__ __launch_bounds__(256) void emit_kernel(
    float* __restrict__ out, const float* __restrict__ thresh,
    const unsigned* __restrict__ present)
{
    int i4 = blockIdx.x * 256 + threadIdx.x;
    int i = i4 * 4;
    int b = i >> 18;
    int p = i & (HW - 1);
    float th = thresh[b];
    unsigned pm = present[b];
    float4 v = reinterpret_cast<float4*>(out)[i4];
    float4 o;
    o.x = ((v.x > th) || ((p + 0) < NC && ((pm >> (p + 0)) & 1u))) ? 1.f : 0.f;
    o.y = ((v.y > th) || ((p + 1) < NC && ((pm >> (p + 1)) & 1u))) ? 1.f : 0.f;
    o.z = ((v.z > th) || ((p + 2) < NC && ((pm >> (p + 2)) & 1u))) ? 1.f : 0.f;
    o.w = ((v.w > th) || ((p + 3) < NC && ((pm >> (p + 3)) & 1u))) ? 1.f : 0.f;
    reinterpret_cast<float4*>(out)[i4] = o;
}

extern "C" void kernel_launch(void* const* d_in, const int* in_sizes, int n_in,
                              void* d_out, int out_size, void* d_ws, size_t ws_size,
                              hipStream_t stream)
{
    const float* logits  = (const float*)d_in[0];
    const int*   targets = (const int*)d_in[1];
    float* out = (float*)d_out;   // doubles as the losses buffer (NPIX floats)

    char* ws = (char*)d_ws;
    unsigned* ghist   = (unsigned*)(ws);                 // 8*4096 u32 = 131072 B
    unsigned* count   = (unsigned*)(ws + 131072);        // 8 u32
    unsigned* present = (unsigned*)(ws + 131104);        // 8 u32
    unsigned* info    = (unsigned*)(ws + 131136);        // 16 u32
    float*    thresh  = (float*)   (ws + 131200);        // 8 f32
    float*    cand    = (float*)   (ws + 131232);        // 8*4096 f32

    hipMemsetAsync(d_ws, 0, 131232, stream);

    losses_kernel<<<LGRID, 64, 0, stream>>>(logits, targets, out, present);
    hist_kernel<<<dim3(64, NB), 256, 0, stream>>>(out, ghist);
    pick_kernel<<<NB, 256, 0, stream>>>(ghist, info);
    compact_kernel<<<dim3(64, NB), 256, 0, stream>>>(out, info, count, cand);
    final_kernel<<<NB, 256, 0, stream>>>(cand, count, info, thresh);
    emit_kernel<<<NPIX / 4 / 256, 256, 0, stream>>>(out, thresh, present);
}

// Round 5
// 115.331 us; speedup vs baseline: 2.7551x; 1.1728x over previous
//
#include <hip/hip_runtime.h>

#define NB 8
#define NC 19
#define HW (512*512)
#define NPIX (NB*HW)
#define RANK 183500u   // max(100000, int(262144*0.7)), < n_pix-1
#define NBIN 4096
#define CAP  4096

__device__ __forceinline__ unsigned fkey(float f) {
    unsigned b = __float_as_uint(f);
    return (b & 0x80000000u) ? ~b : (b | 0x80000000u);
}
__device__ __forceinline__ float finv(unsigned u) {
    unsigned b = (u & 0x80000000u) ? (u & 0x7fffffffu) : ~u;
    return __uint_as_float(b);
}
__device__ __forceinline__ int bin_of(float l) {
    int b = (int)((l + 1.0f) * 224.0f);
    return b < 0 ? 0 : (b > NBIN - 1 ? NBIN - 1 : b);
}
__device__ __forceinline__ unsigned umn(unsigned a, unsigned b) { return a < b ? a : b; }
__device__ __forceinline__ unsigned umx(unsigned a, unsigned b) { return a > b ? a : b; }

// ---------------- Kernel 1: CE losses, 1 pixel/thread, max TLP ----------------
// Block-uniform batch => channel bases live in SGPRs; 19 independent scalar
// loads per thread stay in flight (VGPR ~35 -> 8 waves/SIMD). Per-pixel FP
// sequence is bit-identical to rounds 1-4 (absmax=0 pedigree).
__global__ __launch_bounds__(256) void losses_kernel(
    const float* __restrict__ logits, const int* __restrict__ targets,
    float* __restrict__ losses)
{
    const int blk = blockIdx.x;
    const int bb  = (blk * 256) >> 18;          // block-uniform batch
    const int pp  = (blk * 256) & (HW - 1);     // block-uniform pixel base
    const int tid = threadIdx.x;
    const float* base = logits + (size_t)bb * NC * HW + pp + tid;

    float x[NC];
    #pragma unroll
    for (int c = 0; c < NC; ++c) x[c] = base[(size_t)c * HW];

    const int t = targets[blk * 256 + tid];

    float m = x[0];
    #pragma unroll
    for (int c = 1; c < NC; ++c) m = fmaxf(m, x[c]);

    float s = 0.f, et = 0.f;
    #pragma unroll
    for (int c = 0; c < NC; ++c) {
        float e = expf(x[c] - m);
        s += e;
        if (c == t) et = e;
    }
    float o = 0.f;
    if (t >= 0 && t < NC) o = -logf(et / s + 1e-7f);
    losses[blk * 256 + tid] = o;
}

// ---------------- Kernel 2: per-batch 4096-bin histogram + target presence ----
__global__ __launch_bounds__(256) void hist_kernel(
    const float* __restrict__ losses, const int* __restrict__ targets,
    unsigned* __restrict__ ghist, unsigned* __restrict__ present)
{
    __shared__ unsigned lh[NBIN];
    __shared__ unsigned pres;
    const int b = blockIdx.y;
    for (int j = threadIdx.x; j < NBIN; j += 256) lh[j] = 0;
    if (threadIdx.x == 0) pres = 0u;
    __syncthreads();
    const float4* L = reinterpret_cast<const float4*>(losses + (size_t)b * HW)
                      + (size_t)blockIdx.x * 1024;
    const int4* T = reinterpret_cast<const int4*>(targets + (size_t)b * HW)
                    + (size_t)blockIdx.x * 1024;
    unsigned bits = 0u;
    for (int j = threadIdx.x; j < 1024; j += 256) {
        float4 v = L[j];
        atomicAdd(&lh[bin_of(v.x)], 1u);
        atomicAdd(&lh[bin_of(v.y)], 1u);
        atomicAdd(&lh[bin_of(v.z)], 1u);
        atomicAdd(&lh[bin_of(v.w)], 1u);
        int4 tv = T[j];
        if (tv.x >= 0 && tv.x < NC) bits |= 1u << tv.x;
        if (tv.y >= 0 && tv.y < NC) bits |= 1u << tv.y;
        if (tv.z >= 0 && tv.z < NC) bits |= 1u << tv.z;
        if (tv.w >= 0 && tv.w < NC) bits |= 1u << tv.w;
    }
    #pragma unroll
    for (int o = 1; o < 64; o <<= 1) bits |= __shfl_xor(bits, o);
    if ((threadIdx.x & 63) == 0 && bits) atomicOr(&pres, bits);
    __syncthreads();
    unsigned* gh = ghist + b * NBIN;
    for (int j = threadIdx.x; j < NBIN; j += 256) {
        unsigned v = lh[j];
        if (v) atomicAdd(&gh[j], v);
    }
    if (threadIdx.x == 0 && pres) atomicOr(&present[b], pres);
}

// ---------------- Kernel 3: find rank bin per batch ----------------
__global__ void pick_kernel(const unsigned* __restrict__ ghist,
                            unsigned* __restrict__ info)
{
    __shared__ unsigned lh[NBIN];
    __shared__ unsigned ps[256];
    const int b = blockIdx.x;
    const unsigned* gh = ghist + b * NBIN;
    for (int j = threadIdx.x; j < NBIN; j += 256) lh[j] = gh[j];
    __syncthreads();
    unsigned s = 0;
    for (int j = 0; j < 16; ++j) s += lh[threadIdx.x * 16 + j];
    ps[threadIdx.x] = s;
    __syncthreads();
    if (threadIdx.x == 0) {
        unsigned cum = 0;
        int chunk = 0;
        while (chunk < 255 && cum + ps[chunk] <= RANK) { cum += ps[chunk]; ++chunk; }
        int T = chunk * 16;
        while (T < NBIN - 1 && cum + lh[T] <= RANK) { cum += lh[T]; ++T; }
        info[b * 2]     = (unsigned)T;
        info[b * 2 + 1] = RANK - cum;   // rank within bin T
    }
}

// ---------------- Kernel 4: compact rank-bin elements ----------------
__global__ __launch_bounds__(256) void compact_kernel(
    const float* __restrict__ losses, const unsigned* __restrict__ info,
    unsigned* __restrict__ count, float* __restrict__ cand)
{
    const int b = blockIdx.y;
    const int T = (int)info[b * 2];
    const int lane = threadIdx.x & 63;
    const float4* L = reinterpret_cast<const float4*>(losses + (size_t)b * HW)
                      + (size_t)blockIdx.x * 1024;
    for (int j = threadIdx.x; j < 1024; j += 256) {
        float4 v = L[j];
        float vals[4] = {v.x, v.y, v.z, v.w};
        #pragma unroll
        for (int q = 0; q < 4; ++q) {
            float val = vals[q];
            bool sel = (bin_of(val) == T);
            unsigned long long msk = __ballot(sel);
            if (msk) {
                int leader = __ffsll(msk) - 1;
                int pre = __popcll(msk & ((1ull << lane) - 1ull));
                unsigned base = 0;
                if (lane == leader) base = atomicAdd(&count[b], (unsigned)__popcll(msk));
                base = (unsigned)__shfl((int)base, leader);
                if (sel) {
                    unsigned idx = base + (unsigned)pre;
                    if (idx < CAP) cand[b * CAP + idx] = val;
                }
            }
        }
    }
}

// ---------------- Kernel 5: exact tie-aware rank select (two-level) ----------------
__global__ __launch_bounds__(256) void final_kernel(
    const float* __restrict__ cand, const unsigned* __restrict__ count,
    const unsigned* __restrict__ info, float* __restrict__ thresh)
{
    __shared__ unsigned kf[CAP];
    __shared__ unsigned h[512];
    __shared__ unsigned sub[2048];
    __shared__ unsigned red[8];
    __shared__ unsigned kmin_sh, shift_sh, sb_sh, r2_sh, cnt_sh;
    const int tid = threadIdx.x, b = blockIdx.x;
    unsigned k = count[b]; if (k > CAP) k = CAP;
    const unsigned r = info[b * 2 + 1];

    for (unsigned j = tid; j < k; j += 256) kf[j] = fkey(cand[b * CAP + j]);
    for (int j = tid; j < 512; j += 256) h[j] = 0;
    __syncthreads();

    unsigned lmin = 0xFFFFFFFFu, lmax = 0u;
    for (unsigned j = tid; j < k; j += 256) { unsigned v = kf[j]; lmin = umn(lmin, v); lmax = umx(lmax, v); }
    #pragma unroll
    for (int o = 1; o < 64; o <<= 1) {
        lmin = umn(lmin, (unsigned)__shfl_xor((int)lmin, o));
        lmax = umx(lmax, (unsigned)__shfl_xor((int)lmax, o));
    }
    if ((tid & 63) == 0) { red[tid >> 6] = lmin; red[4 + (tid >> 6)] = lmax; }
    __syncthreads();
    if (tid == 0) {
        unsigned mn = red[0], mx = red[4];
        for (int w = 1; w < 4; ++w) { mn = umn(mn, red[w]); mx = umx(mx, red[4 + w]); }
        unsigned spread = mx - mn;
        int bits = 32 - __clz((int)(spread | 1u));
        shift_sh = (unsigned)(bits > 9 ? bits - 9 : 0);   // (spread>>shift) < 512
        kmin_sh = mn;
        cnt_sh = 0;
    }
    __syncthreads();
    const unsigned kmin = kmin_sh, shift = shift_sh;
    for (unsigned j = tid; j < k; j += 256) atomicAdd(&h[(kf[j] - kmin) >> shift], 1u);
    __syncthreads();
    if (tid == 0) {
        unsigned cum = 0; int sb = 0;
        while (sb < 511 && cum + h[sb] <= r) { cum += h[sb]; ++sb; }
        sb_sh = (unsigned)sb; r2_sh = r - cum;
    }
    __syncthreads();
    const unsigned sb = sb_sh;
    for (unsigned j = tid; j < k; j += 256) {
        if (((kf[j] - kmin) >> shift) == sb) {
            unsigned idx = atomicAdd(&cnt_sh, 1u);
            if (idx < 2048) sub[idx] = kf[j];
        }
    }
    __syncthreads();
    const unsigned k2 = umn(cnt_sh, 2048u), r2 = r2_sh;
    for (unsigned e = tid; e < k2; e += 256) {
        unsigned v = sub[e], less = 0, eq = 0;
        for (unsigned j = 0; j < k2; ++j) { unsigned u = sub[j]; less += (u < v); eq += (u == v); }
        if (less <= r2 && r2 < less + eq) thresh[b] = finv(v);
    }
}

// ---------------- Kernel 6: losses -> selection flags (in place) ----------------
__global__ __launch_bounds__(256) void emit_kernel(
    float* __restrict__ out, const float* __restrict__ thresh,
    const unsigned* __restrict__ present)
{
    int i4 = blockIdx.x * 256 + threadIdx.x;
    int i = i4 * 4;
    int b = i >> 18;
    int p = i & (HW - 1);
    float th = thresh[b];
    unsigned pm = present[b];
    float4 v = reinterpret_cast<float4*>(out)[i4];
    float4 o;
    o.x = ((v.x > th) || ((p + 0) < NC && ((pm >> (p + 0)) & 1u))) ? 1.f : 0.f;
    o.y = ((v.y > th) || ((p + 1) < NC && ((pm >> (p + 1)) & 1u))) ? 1.f : 0.f;
    o.z = ((v.z > th) || ((p + 2) < NC && ((pm >> (p + 2)) & 1u))) ? 1.f : 0.f;
    o.w = ((v.w > th) || ((p + 3) < NC && ((pm >> (p + 3)) & 1u))) ? 1.f : 0.f;
    reinterpret_cast<float4*>(out)[i4] = o;
}

extern "C" void kernel_launch(void* const* d_in, const int* in_sizes, int n_in,
                              void* d_out, int out_size, void* d_ws, size_t ws_size,
                              hipStream_t stream)
{
    const float* logits  = (const float*)d_in[0];
    const int*   targets = (const int*)d_in[1];
    float* out = (float*)d_out;   // doubles as the losses buffer (NPIX floats)

    char* ws = (char*)d_ws;
    unsigned* ghist   = (unsigned*)(ws);                 // 8*4096 u32 = 131072 B
    unsigned* count   = (unsigned*)(ws + 131072);        // 8 u32
    unsigned* present = (unsigned*)(ws + 131104);        // 8 u32
    unsigned* info    = (unsigned*)(ws + 131136);        // 16 u32
    float*    thresh  = (float*)   (ws + 131200);        // 8 f32
    float*    cand    = (float*)   (ws + 131232);        // 8*4096 f32

    hipMemsetAsync(d_ws, 0, 131232, stream);

    losses_kernel<<<NPIX / 256, 256, 0, stream>>>(logits, targets, out);
    hist_kernel<<<dim3(64, NB), 256, 0, stream>>>(out, targets, ghist, present);
    pick_kernel<<<NB, 256, 0, stream>>>(ghist, info);
    compact_kernel<<<dim3(64, NB), 256, 0, stream>>>(out, info, count, cand);
    final_kernel<<<NB, 256, 0, stream>>>(cand, count, info, thresh);
    emit_kernel<<<NPIX / 4 / 256, 256, 0, stream>>>(out, thresh, present);
}